// Round 6
// baseline (63.058 us; speedup 1.0000x reference)
//
#include <hip/hip_runtime.h>

#define SL 10
#define NI 128

typedef float f32x4 __attribute__((ext_vector_type(4)));
typedef unsigned int u32;
typedef u32 u32x4 __attribute__((ext_vector_type(4)));
typedef _Float16 h8 __attribute__((ext_vector_type(8)));
typedef _Float16 h4 __attribute__((ext_vector_type(4)));

__device__ __forceinline__ f32x4 MFH(h8 a, h8 b, f32x4 c){
  return __builtin_amdgcn_mfma_f32_16x16x32_f16(a, b, c, 0, 0, 0);
}
__device__ __forceinline__ float sigf(float x){ return __fdividef(1.f, 1.f + __expf(-x)); }
__device__ __forceinline__ float tanhf2(float x){ return __fdividef(2.f, 1.f + __expf(-2.f*x)) - 1.f; }

__device__ __forceinline__ h8 to_h8(float4 a, float4 b){
  h8 r;
  r[0]=(_Float16)a.x; r[1]=(_Float16)a.y; r[2]=(_Float16)a.z; r[3]=(_Float16)a.w;
  r[4]=(_Float16)b.x; r[5]=(_Float16)b.y; r[6]=(_Float16)b.z; r[7]=(_Float16)b.w;
  return r;
}

// One wave (64 threads) per 16 batch rows, zero barriers.
// x is read in 2-TIMESTEP PAGE BURSTS: per burst each of the 16 rows is read as
// one CONTIGUOUS 1KB span (full DRAM page per activate, vs 512B granules in
// r1-r5 which capped delivered BW at ~3.3 TB/s). Lane l covers row l>>2,
// 256B chunk l&3 (16 x float4). f32->f16 cvt, transpose-write into a
// wave-private XOR-swizzled LDS tile (double-buffered by pair parity,
// in-order DS pipe, no s_barrier), swizzled ds_read_b128 -> B fragments.
//   A = weights (gate-permuted rows: tile nt, A-row lr -> gate (lr&3)*20+(lr>>2)+nt*4),
//   B = x/h (col = batch row lr). C-reg i of lane (lr,lg) = gate type i of unit
//   nt*4+lg for batch col lr -> fp32 gate math fully in-register.
//   h exchange via 2KB wave-private LDS (stride 33), no barrier.
// XT layout: XT[par][row][step][256B], swizzle: boff ^= (row&7)<<4 (bits 4-6,
// preserves 16B alignment; read lanes spread 2-way across banks = free).
__global__ __launch_bounds__(64, 2) void bilstm_kernel(
    const float* __restrict__ x,
    const float* __restrict__ Wih_f, const float* __restrict__ Whh_f,
    const float* __restrict__ bih_f, const float* __restrict__ bhh_f,
    const float* __restrict__ Wih_b,
    const float* __restrict__ bih_b, const float* __restrict__ bhh_b,
    float* __restrict__ out)
{
  __shared__ __attribute__((aligned(16))) char XT[2][8192];  // [par][16 rows][2 steps][256B]
  __shared__ u32 HB[16*33];                                  // h exchange, stride 33

  const int l  = threadIdx.x;
  const int lr = l & 15;
  const int lg = l >> 4;
  const int r  = l >> 2;        // burst row (0..15)
  const int c  = l & 3;         // 256B chunk within row's 1KB pair-span
  const long b0 = (long)blockIdx.x * 16;
  const int gb = (lr&3)*20 + (lr>>2);

  for(int i=l;i<16*33;i+=64) HB[i]=0;

  // write-side invariants: step = c>>1, f16 base byte = (c&1)*128, swizzle (r&7)<<4
  const int wbase = r*512 + (c>>1)*256;
  const int wkh   = (c&1)*128;
  const int wswz  = (r&7)<<4;
  const int rswz  = (lr&7)<<4;

  // ---- prologue: issue burst for pair 0 (t=0,1): 16 rows x 1KB contiguous ----
  const float* xbase = x + (b0+r)*(long)(SL*NI) + c*64;
  float4 buf[16];
  #pragma unroll
  for(int i=0;i<16;i++) buf[i] = *(const float4*)(xbase + i*4);

  // ---- W_ih_f fragments (f16), register-resident ----
  h8 WIH[20];
  #pragma unroll
  for(int p=0;p<20;p++){
    const int nt=p>>2, ks=p&3;
    const float* s = Wih_f + (gb+nt*4)*NI + ks*32 + lg*8;
    WIH[p] = to_h8(*(const float4*)s, *(const float4*)(s+4));
  }
  // ---- W_hh_f fragments (K=20 zero-padded to 32) ----
  h8 WHH[5];
  #pragma unroll
  for(int nt=0;nt<5;nt++){
    h8 w;
    #pragma unroll
    for(int j=0;j<8;j++){
      const int k = lg*8+j;
      w[j] = (_Float16)((k<20) ? Whh_f[(gb+nt*4)*20+k] : 0.f);
    }
    WHH[nt]=w;
  }
  // ---- forward bias, packed f16 ----
  h4 bp[5];
  #pragma unroll
  for(int nt=0;nt<5;nt++)
    #pragma unroll
    for(int ty=0;ty<4;ty++)
      bp[nt][ty] = (_Float16)(bih_f[ty*20+nt*4+lg] + bhh_f[ty*20+nt*4+lg]);

  float cst[5]={0.f,0.f,0.f,0.f,0.f};
  h8 bx[4];
  f32x4 acc[5];

  #pragma unroll
  for(int p=0;p<5;p++){
    char* const xt = XT[p&1];
    // ---- stage pair p: cvt f32->f16, swizzled transpose-write (16x ds_write_b64)
    #pragma unroll
    for(int i=0;i<16;i++){
      float4 v = buf[i];
      h4 hv; hv[0]=(_Float16)v.x; hv[1]=(_Float16)v.y; hv[2]=(_Float16)v.z; hv[3]=(_Float16)v.w;
      *(h4*)(xt + wbase + ((wkh + i*8) ^ wswz)) = hv;
    }
    // ---- issue page burst for pair p+1 (in flight across both steps' compute)
    if(p<4){
      #pragma unroll
      for(int i=0;i<16;i++) buf[i] = *(const float4*)(xbase + (p+1)*256 + i*4);
    }
    // ---- two timesteps from this pair ----
    #pragma unroll
    for(int s=0;s<2;s++){
      const int t = 2*p+s;
      const char* rb = xt + lr*512 + s*256;
      #pragma unroll
      for(int ks=0;ks<4;ks++)
        bx[ks] = *(const h8*)(rb + ((ks*64 + lg*16) ^ rswz));
      u32x4 hb0, hb1;
      if(t>0){
        const u32* hp = HB + lr*33 + lg*8;
        hb0=*(const u32x4*)hp; hb1=*(const u32x4*)(hp+4);
      }
      #pragma unroll
      for(int nt=0;nt<5;nt++){
        acc[nt][0]=(float)bp[nt][0]; acc[nt][1]=(float)bp[nt][1];
        acc[nt][2]=(float)bp[nt][2]; acc[nt][3]=(float)bp[nt][3];
      }
      // projection: 20 MFMAs
      #pragma unroll
      for(int ks=0;ks<4;ks++)
        #pragma unroll
        for(int nt=0;nt<5;nt++)
          acc[nt]=MFH(WIH[nt*4+ks], bx[ks], acc[nt]);
      // recurrence: 10 MFMAs (h 2-term f16)
      if(t>0){
        u32x4 hh, hl;
        hh[0]=(hb0[0]>>16)|(hb0[1]&0xffff0000u);
        hh[1]=(hb0[2]>>16)|(hb0[3]&0xffff0000u);
        hh[2]=(hb1[0]>>16)|(hb1[1]&0xffff0000u);
        hh[3]=(hb1[2]>>16)|(hb1[3]&0xffff0000u);
        hl[0]=(hb0[0]&0xffffu)|(hb0[1]<<16);
        hl[1]=(hb0[2]&0xffffu)|(hb0[3]<<16);
        hl[2]=(hb1[0]&0xffffu)|(hb1[1]<<16);
        hl[3]=(hb1[2]&0xffffu)|(hb1[3]<<16);
        h8 fh=__builtin_bit_cast(h8,hh), fl=__builtin_bit_cast(h8,hl);
        #pragma unroll
        for(int nt=0;nt<5;nt++){
          acc[nt]=MFH(WHH[nt], fh, acc[nt]);
          acc[nt]=MFH(WHH[nt], fl, acc[nt]);
        }
      }
      // in-register fp32 gate math
      #pragma unroll
      for(int nt=0;nt<5;nt++){
        float ig=sigf(acc[nt][0]);
        float fg=sigf(acc[nt][1]);
        float gg=tanhf2(acc[nt][2]);
        float og=sigf(acc[nt][3]);
        cst[nt]=fg*cst[nt]+ig*gg;
        float hv=og*tanhf2(cst[nt]);
        if(t==SL-1){
          out[(b0+lr)*40 + nt*4+lg] = hv;
        } else {
          _Float16 hh16=(_Float16)hv;
          _Float16 hl16=(_Float16)(hv-(float)hh16);
          HB[lr*33 + nt*4+lg] = ((u32)__builtin_bit_cast(unsigned short,hh16)<<16)
                                | (u32)__builtin_bit_cast(unsigned short,hl16);
        }
      }
    }
  }

  // ---- backward direction: one step, h0=c0=0, bx still holds x[t=9] frags ----
  f32x4 a2[5];
  #pragma unroll
  for(int nt=0;nt<5;nt++)
    #pragma unroll
    for(int ty=0;ty<4;ty++)
      a2[nt][ty] = bih_b[ty*20+nt*4+lg] + bhh_b[ty*20+nt*4+lg];
  #pragma unroll
  for(int ks=0;ks<4;ks++){
    #pragma unroll
    for(int nt=0;nt<5;nt++){
      const float* s = Wih_b + (gb+nt*4)*NI + ks*32 + lg*8;
      a2[nt]=MFH(to_h8(*(const float4*)s, *(const float4*)(s+4)), bx[ks], a2[nt]);
    }
  }
  #pragma unroll
  for(int nt=0;nt<5;nt++){
    float ig=sigf(a2[nt][0]);
    float gg=tanhf2(a2[nt][2]);
    float og=sigf(a2[nt][3]);
    out[(b0+lr)*40 + 20 + nt*4+lg] = og*tanhf2(ig*gg);   // c = i*g (f-gate hits c0=0)
  }
}

extern "C" void kernel_launch(void* const* d_in, const int* in_sizes, int n_in,
                              void* d_out, int out_size, void* d_ws, size_t ws_size,
                              hipStream_t stream) {
  const float* x     = (const float*)d_in[0];
  const float* Wih_f = (const float*)d_in[1];
  const float* Whh_f = (const float*)d_in[2];
  const float* bih_f = (const float*)d_in[3];
  const float* bhh_f = (const float*)d_in[4];
  const float* Wih_b = (const float*)d_in[5];
  // d_in[6] = W_hh_b: provably unused (hs_b[0] has h0 = 0)
  const float* bih_b = (const float*)d_in[7];
  const float* bhh_b = (const float*)d_in[8];
  float* out = (float*)d_out;
  bilstm_kernel<<<dim3(2048), dim3(64), 0, stream>>>(
      x, Wih_f, Whh_f, bih_f, bhh_f, Wih_b, bih_b, bhh_b, out);
}